// Round 2
// baseline (542.967 us; speedup 1.0000x reference)
//
#include <hip/hip_runtime.h>
#include <math.h>

// ---------------- scores: s_i = sigmoid(x_i . w + b), fp64 accumulate ----------------
__global__ __launch_bounds__(256) void scores_kernel(
    const float* __restrict__ x, const float* __restrict__ w,
    const float* __restrict__ bptr, int N, int F, unsigned* __restrict__ scores) {
  int node = blockIdx.x * 4 + (threadIdx.x >> 6);
  int lane = threadIdx.x & 63;
  if (node >= N) return;
  const float* xr = x + (size_t)node * F;
  double acc = 0.0;
  for (int f = lane; f < F; f += 64)
    acc += (double)xr[f] * (double)w[f];
  for (int off = 32; off > 0; off >>= 1)
    acc += __shfl_down(acc, off, 64);
  if (lane == 0) {
    double z = acc + (double)bptr[0];
    double s = 1.0 / (1.0 + exp(-z));
    scores[node] = __float_as_uint((float)s);   // positive floats: bits are order-monotone
  }
}

// ---------------- radix-select histograms (pass 0: hi16, pass 1: lo16 within bucket) ----
__global__ __launch_bounds__(256) void hist_kernel(
    const unsigned* __restrict__ scores, int N, unsigned* __restrict__ hist,
    const unsigned* __restrict__ sel, int pass) {
  int i = blockIdx.x * 256 + threadIdx.x;
  if (i >= N) return;
  unsigned bits = scores[i];
  if (pass == 0) {
    atomicAdd(&hist[bits >> 16], 1u);
  } else {
    if ((bits >> 16) == sel[0]) atomicAdd(&hist[bits & 0xFFFFu], 1u);
  }
}

// find bucket containing rank q (ascending); outB = bucket, outRem = rank within bucket
__global__ __launch_bounds__(256) void select_kernel(
    const unsigned* __restrict__ hist, const unsigned* __restrict__ qptr, unsigned qconst,
    unsigned* __restrict__ outB, unsigned* __restrict__ outRem) {
  __shared__ unsigned tot[256];
  __shared__ unsigned bins[256];
  __shared__ unsigned sChunk, sRem;
  int t = threadIdx.x;
  unsigned q = qptr ? *qptr : qconst;
  const unsigned* hp = hist + t * 256;
  unsigned s = 0;
  for (int j = 0; j < 256; j++) s += hp[j];
  tot[t] = s;
  __syncthreads();
  if (t == 0) {
    unsigned cum = 0; int c = 0;
    for (; c < 256; c++) { if (q < cum + tot[c]) break; cum += tot[c]; }
    sChunk = (unsigned)c; sRem = q - cum;
  }
  __syncthreads();
  bins[t] = hist[sChunk * 256 + t];
  __syncthreads();
  if (t == 0) {
    unsigned cum = 0; unsigned q2 = sRem; int bi = 0;
    for (; bi < 256; bi++) { if (q2 < cum + bins[bi]) break; cum += bins[bi]; }
    *outB = sChunk * 256 + bi;
    *outRem = q2 - cum;
  }
}

// ---------------- node mask block sums ----------------
__global__ __launch_bounds__(256) void node_mask_sums(
    const unsigned* __restrict__ scores, const unsigned* __restrict__ sel, int N,
    unsigned* __restrict__ sums) {
  int i = blockIdx.x * 256 + threadIdx.x;
  unsigned T = (sel[0] << 16) | sel[2];
  int m = (i < N) && (scores[i] >= T);
  unsigned long long bal = __ballot(m);
  __shared__ unsigned wv[4];
  int lane = threadIdx.x & 63, wave = threadIdx.x >> 6;
  if (lane == 0) wv[wave] = (unsigned)__popcll(bal);
  __syncthreads();
  if (threadIdx.x == 0) sums[blockIdx.x] = wv[0] + wv[1] + wv[2] + wv[3];
}

// ---------------- in-place exclusive scan, single block, chunked 256 ----------------
__global__ __launch_bounds__(256) void scan_exclusive(unsigned* __restrict__ data, int n) {
  __shared__ unsigned tmp[256];
  __shared__ unsigned carry;
  int t = threadIdx.x;
  if (t == 0) carry = 0;
  __syncthreads();
  for (int base = 0; base < n; base += 256) {
    int i = base + t;
    unsigned v = (i < n) ? data[i] : 0;
    tmp[t] = v;
    __syncthreads();
    for (int s = 1; s < 256; s <<= 1) {
      unsigned a = (t >= s) ? tmp[t - s] : 0;
      __syncthreads();
      tmp[t] += a;
      __syncthreads();
    }
    unsigned incl = tmp[t];
    unsigned c = carry;
    if (i < n) data[i] = c + incl - v;
    unsigned total = tmp[255];
    __syncthreads();
    if (t == 0) carry = c + total;
    __syncthreads();
  }
}

// ---------------- node finalize: mapping, pool_indices (fp32), pool source list ----------
__global__ __launch_bounds__(256) void node_finalize(
    const unsigned* __restrict__ scores, const unsigned* __restrict__ sel,
    const unsigned* __restrict__ sums_ex, int N, int n_keep,
    int* __restrict__ map, int* __restrict__ poolsrc, float* __restrict__ out_pool) {
  int i = blockIdx.x * 256 + threadIdx.x;
  unsigned T = (sel[0] << 16) | sel[2];
  int m = (i < N) && (scores[i] >= T);
  unsigned long long bal = __ballot(m);
  int lane = threadIdx.x & 63, wave = threadIdx.x >> 6;
  __shared__ unsigned wv[4];
  if (lane == 0) wv[wave] = (unsigned)__popcll(bal);
  __syncthreads();
  unsigned pre = 0;
  for (int k = 0; k < wave; k++) pre += wv[k];
  pre += (unsigned)__popcll(bal & ((1ull << lane) - 1ull));
  if (i < N) {
    int mv = -1;
    if (m) {
      unsigned rank = sums_ex[blockIdx.x] + pre;
      if (rank < (unsigned)n_keep) {
        mv = (int)rank;
        poolsrc[rank] = i;
        out_pool[rank] = (float)i;
      }
    }
    map[i] = mv;
  }
}

// ---------------- new_x gather (fp32 rows, float2/lane, 1 wave per row) ----------------
__global__ __launch_bounds__(256) void gather_x(
    const float* __restrict__ x, const int* __restrict__ poolsrc, int n_keep, int F, int N,
    float* __restrict__ outx) {
  int r = blockIdx.x * 4 + (threadIdx.x >> 6);
  int lane = threadIdx.x & 63;
  if (r >= n_keep) return;
  int src = poolsrc[r];
  src = src < 0 ? 0 : (src >= N ? N - 1 : src);  // insurance against bad rank logic
  const float2* s = (const float2*)(x + (size_t)src * F);
  float2* d = (float2*)(outx + (size_t)r * F);
  int half = F / 2;  // 64
  for (int j = lane; j < half; j += 64) d[j] = s[j];
}

// ---------------- edge mask: pool_edges output (fp32 0/1) + block sums ----------------
__global__ __launch_bounds__(256) void edge_mask_sums(
    const int* __restrict__ ei, const int* __restrict__ map, int E,
    float* __restrict__ out_pe, unsigned* __restrict__ sums) {
  int e = blockIdx.x * 256 + threadIdx.x;
  int m = 0;
  if (e < E) {
    int a = ei[e], b = ei[E + e];
    m = (map[a] >= 0) && (map[b] >= 0);
    out_pe[e] = m ? 1.0f : 0.0f;
  }
  unsigned long long bal = __ballot(m);
  __shared__ unsigned wv[4];
  int lane = threadIdx.x & 63, wave = threadIdx.x >> 6;
  if (lane == 0) wv[wave] = (unsigned)__popcll(bal);
  __syncthreads();
  if (threadIdx.x == 0) sums[blockIdx.x] = wv[0] + wv[1] + wv[2] + wv[3];
}

// ---------------- edge finalize: compact indices, remapped indices, attrs (all fp32) -----
__global__ __launch_bounds__(256) void edge_finalize(
    const int* __restrict__ ei, const int* __restrict__ map,
    const unsigned* __restrict__ sums_ex, int E, int Ek, int Fe,
    const float* __restrict__ attr, float* __restrict__ out,
    size_t o_ei, size_t o_eio, size_t o_attr) {
  int e = blockIdx.x * 256 + threadIdx.x;
  int m = 0, a = 0, b = 0, ma = -1, mb = -1;
  if (e < E) {
    a = ei[e]; b = ei[E + e];
    ma = map[a]; mb = map[b];
    m = (ma >= 0) && (mb >= 0);
  }
  unsigned long long bal = __ballot(m);
  int lane = threadIdx.x & 63, wave = threadIdx.x >> 6;
  __shared__ unsigned wv[4];
  if (lane == 0) wv[wave] = (unsigned)__popcll(bal);
  __syncthreads();
  unsigned pre = 0;
  for (int k = 0; k < wave; k++) pre += wv[k];
  pre += (unsigned)__popcll(bal & ((1ull << lane) - 1ull));
  if (m) {
    unsigned p = sums_ex[blockIdx.x] + pre;
    out[o_ei + p]              = (float)a;
    out[o_ei + (size_t)Ek + p] = (float)b;
    out[o_eio + p]              = (float)ma;
    out[o_eio + (size_t)Ek + p] = (float)mb;
    float4* dst = (float4*)(out + o_attr + (size_t)p * Fe);
    const float4* src = (const float4*)(attr + (size_t)e * Fe);
    for (int j = 0; j < Fe / 4; j++) dst[j] = src[j];
  }
}

extern "C" void kernel_launch(void* const* d_in, const int* in_sizes, int n_in,
                              void* d_out, int out_size, void* d_ws, size_t ws_size,
                              hipStream_t stream) {
  const int F  = in_sizes[2];        // 128
  const int E  = in_sizes[4] / 2;    // 1,600,000
  const int N  = in_sizes[0] / F;    // 100,000
  const int Fe = in_sizes[1] / E;    // 32
  const int n_keep = N / 2;          // int(N * K_FRAC), K_FRAC = 0.5
  const unsigned q = (unsigned)(N - n_keep - 1);  // kth-1 (0-based ascending order stat)
  // out_size = n_keep*F + 2Ek + 2Ek + Ek*Fe + n_keep + E  =>  solve for Ek
  const int Ek = (int)(((long long)out_size - (long long)n_keep * F - n_keep - E) / (4 + Fe));

  const float* x    = (const float*)d_in[0];
  const float* attr = (const float*)d_in[1];
  const float* w    = (const float*)d_in[2];
  const float* b    = (const float*)d_in[3];
  const int*   ei   = (const int*)d_in[4];
  float*       out  = (float*)d_out;

  const size_t o_newx = 0;
  const size_t o_ei   = (size_t)n_keep * F;
  const size_t o_eio  = o_ei + 2 * (size_t)Ek;
  const size_t o_attr = o_eio + 2 * (size_t)Ek;
  const size_t o_pool = o_attr + (size_t)Ek * Fe;
  const size_t o_pe   = o_pool + (size_t)n_keep;

  // workspace carve (256B aligned regions), total ~1.6 MB
  char* wsb = (char*)d_ws;
  size_t off = 0;
  auto carve = [&](size_t bytes) -> void* {
    void* p = wsb + off;
    off = (off + bytes + 255) & ~(size_t)255;
    return p;
  };
  const int nb_n = (N + 255) / 256;
  const int nb_e = (E + 255) / 256;
  unsigned* scores = (unsigned*)carve((size_t)N * 4);
  unsigned* hist1  = (unsigned*)carve((size_t)65536 * 4);
  unsigned* hist2  = (unsigned*)carve((size_t)65536 * 4);  // contiguous with hist1
  unsigned* sel    = (unsigned*)carve(64);
  unsigned* nsum   = (unsigned*)carve((size_t)nb_n * 4);
  unsigned* esum   = (unsigned*)carve((size_t)nb_e * 4);
  int* map         = (int*)carve((size_t)N * 4);
  int* poolsrc     = (int*)carve((size_t)n_keep * 4);

  hipMemsetAsync(hist1, 0, (size_t)2 * 65536 * 4, stream);
  scores_kernel<<<(N + 3) / 4, 256, 0, stream>>>(x, w, b, N, F, scores);
  hist_kernel<<<nb_n, 256, 0, stream>>>(scores, N, hist1, sel, 0);
  select_kernel<<<1, 256, 0, stream>>>(hist1, nullptr, q, sel + 0, sel + 1);
  hist_kernel<<<nb_n, 256, 0, stream>>>(scores, N, hist2, sel, 1);
  select_kernel<<<1, 256, 0, stream>>>(hist2, sel + 1, 0u, sel + 2, sel + 3);
  node_mask_sums<<<nb_n, 256, 0, stream>>>(scores, sel, N, nsum);
  scan_exclusive<<<1, 256, 0, stream>>>(nsum, nb_n);
  node_finalize<<<nb_n, 256, 0, stream>>>(scores, sel, nsum, N, n_keep, map, poolsrc, out + o_pool);
  gather_x<<<(n_keep + 3) / 4, 256, 0, stream>>>(x, poolsrc, n_keep, F, N, out + o_newx);
  edge_mask_sums<<<nb_e, 256, 0, stream>>>(ei, map, E, out + o_pe, esum);
  scan_exclusive<<<1, 256, 0, stream>>>(esum, nb_e);
  edge_finalize<<<nb_e, 256, 0, stream>>>(ei, map, esum, E, Ek, Fe, attr,
                                          out, o_ei, o_eio, o_attr);
}